// Round 6
// baseline (175.323 us; speedup 1.0000x reference)
//
#include <hip/hip_runtime.h>
#include <stdint.h>
#include <math.h>

typedef __attribute__((ext_vector_type(8))) short short8;
typedef __attribute__((ext_vector_type(4))) float floatx4;

// ---------------- LDS layout (26624 B -> 4 blocks/CU at 8 waves) ----------------
#define L_HF    0        // 16384: W1 B-frags, then h B-frags: [ct(4)][ks(4)][lane(64)] x 16B
#define L_SRC   16384    // 2048 : att_src [4][128] f32 (pre-scaled by log2e)
#define L_DST   18432    // 2048 : att_dst [4][128] f32 (pre-scaled by log2e)
#define L_MASK  20480    // 2048 : mask bits [128 rows][16 B]
#define L_H2P   22528    // 4096 : layer-2 partials float2[4 heads][128 nodes]
#define L_SIZE  26624

union F8 { short8 s8; uint32_t u[4]; };

#if __has_builtin(__builtin_amdgcn_exp2f)
#define EXP2F __builtin_amdgcn_exp2f
#else
#define EXP2F exp2f
#endif
#define LOG2E 1.4426950408889634f

__device__ __forceinline__ uint32_t packbf(float a, float b){
  uint32_t ua = __float_as_uint(a), ub = __float_as_uint(b);
  uint32_t ra = (ua + 0x7fffu + ((ua>>16)&1u)) >> 16;   // RNE bf16
  uint32_t rb = (ub + 0x7fffu + ((ub>>16)&1u)) >> 16;
  return ra | (rb<<16);
}
// truncation pack (1 inst): low16 = hi16(a), high16 = hi16(b)
__device__ __forceinline__ uint32_t packbf_t(float a, float b){
  return __builtin_amdgcn_perm(__float_as_uint(b), __float_as_uint(a), 0x07060302u);
}
__device__ __forceinline__ float fast_tanh(float x){
  float e = __expf(2.f*x);
  return 1.f - 2.f*__builtin_amdgcn_rcpf(e + 1.f);
}
// sum over the 16-lane DPP row via row_ror — result valid in ALL lanes. Pure VALU.
__device__ __forceinline__ float red16(float x){
  x += __int_as_float(__builtin_amdgcn_update_dpp(0, __float_as_int(x), 0x128, 0xf, 0xf, true)); // row_ror:8
  x += __int_as_float(__builtin_amdgcn_update_dpp(0, __float_as_int(x), 0x124, 0xf, 0xf, true)); // row_ror:4
  x += __int_as_float(__builtin_amdgcn_update_dpp(0, __float_as_int(x), 0x122, 0xf, 0xf, true)); // row_ror:2
  x += __int_as_float(__builtin_amdgcn_update_dpp(0, __float_as_int(x), 0x121, 0xf, 0xf, true)); // row_ror:1
  return x;
}

// ---- fused GAT: one block per (s, b, head-half), 8 waves ----
__global__ __launch_bounds__(512,8) void gat_fused(
    const float* __restrict__ x,  const float* __restrict__ emb,
    const int* __restrict__ adj,  const float* __restrict__ w1,
    const float* __restrict__ a_src1, const float* __restrict__ a_dst1,
    const float* __restrict__ b1, const float* __restrict__ w2,
    float* __restrict__ ws_h2)
{
  __shared__ __align__(16) char smem[L_SIZE];
  char*     hf    = smem + L_HF;
  uint32_t* hf_u  = (uint32_t*)(smem + L_HF);
  float*    src_l = (float*)(smem + L_SRC);
  float*    dst_l = (float*)(smem + L_DST);
  uint32_t* mask_l= (uint32_t*)(smem + L_MASK);
  float2*   h2p   = (float2*)(smem + L_H2P);

  const int t    = threadIdx.x;
  const int blk  = blockIdx.x;
  const int s    = blk >> 8;
  const int bb   = (blk & 255) >> 1;
  const int half = blk & 1;
  const int lane = t & 63, w = t >> 6;
  const int of = lane & 15, kg = lane >> 4;

  // ---------- Phase 0a: A-frags direct from global (rows w*16+of) ----------
  const int arow = w*16 + of;
  const float* xrow = x   + ((size_t)bb*128 + arow)*64;
  const float* erow = emb + ((size_t)bb*128 + arow)*64;
  short8 af[4];
  #pragma unroll
  for (int ks=0; ks<4; ++ks){
    int k = ks*32 + kg*8;
    const float* p = (k<64) ? (xrow+k) : (erow + (k-64));
    float4 f0 = *(const float4*)p, f1 = *(const float4*)(p+4);
    F8 fr;
    fr.u[0]=packbf(f0.x,f0.y); fr.u[1]=packbf(f0.z,f0.w);
    fr.u[2]=packbf(f1.x,f1.y); fr.u[3]=packbf(f1.z,f1.w);
    af[ks]=fr.s8;
  }

  // ---------- Phase 0b: stage this block's 4 heads of W1 as bf16 B-frags ----------
  {
    const float* w1s = w1 + (size_t)s*16384 + half*8192;  // 4 heads x 128 x 16
    #pragma unroll
    for (int r=0; r<2; ++r){
      int q = t + r*512;                     // 0..1023 = (ct*4+ks)*64 + qlane
      int ql = q & 63, ks = (q>>6)&3, ct = q>>8;
      const float* wp = w1s + ct*2048 + (ks*32 + (ql>>4)*8)*16 + (ql&15);
      F8 fr;
      fr.u[0]=packbf(wp[0],  wp[16]);
      fr.u[1]=packbf(wp[32], wp[48]);
      fr.u[2]=packbf(wp[64], wp[80]);
      fr.u[3]=packbf(wp[96], wp[112]);
      *(short8*)(hf + ((ct*4+ks)*64 + ql)*16) = fr.s8;
    }
  }

  // ---------- Phase 0c: adjacency ballot -> mask bits (wave w: rows w*16..+15) ----------
  {
    const int* adjb = adj + (size_t)bb*16384;
    #pragma unroll 4
    for (int rr=0; rr<16; ++rr){
      const int row = w*16 + rr;
      const int* ar = adjb + row*128;
      uint64_t m0 = __ballot(ar[lane] != 0);
      uint64_t m1 = __ballot(ar[64+lane] != 0);
      if (lane == 0)
        ((uint4*)mask_l)[row] = make_uint4((uint32_t)m0,(uint32_t)(m0>>32),
                                           (uint32_t)m1,(uint32_t)(m1>>32));
    }
  }
  __syncthreads();

  // ---------- Phase 1: h = x0 @ W1 via MFMA ----------
  floatx4 acc[4];
  #pragma unroll
  for (int ct=0; ct<4; ++ct) acc[ct]=(floatx4){0.f,0.f,0.f,0.f};
  #pragma unroll
  for (int ct=0; ct<4; ++ct)
    #pragma unroll
    for (int ks=0; ks<4; ++ks){
      short8 bfr = *(const short8*)(hf + ((ct*4+ks)*64 + lane)*16);
      acc[ct] = __builtin_amdgcn_mfma_f32_16x16x32_bf16(af[ks], bfr, acc[ct], 0,0,0);
    }
  __syncthreads();                            // all W1-frag reads done before h overwrite

  // epilogue: tanh -> att partials (x log2e) via DPP row-reduce; h -> LDS in B-frag order
  const int ks_h = w>>1, kgp = (w&1)*2 + (kg>>1), vv = (kg&1)*2;
  #pragma unroll
  for (int ct=0; ct<4; ++ct){
    const int ghd = half*4 + ct;
    float asv = a_src1[s*128 + ghd*16 + of] * LOG2E;
    float adv = a_dst1[s*128 + ghd*16 + of] * LOG2E;
    float ps[4], pd[4];
    #pragma unroll
    for (int r=0; r<4; ++r){
      float th = fast_tanh(acc[ct][r]);
      ps[r] = red16(th*asv); pd[r] = red16(th*adv);
    }
    if (of==0){
      #pragma unroll
      for (int r=0; r<4; ++r){
        int i = w*16 + kg*4 + r;
        src_l[ct*128+i]=ps[r]; dst_l[ct*128+i]=pd[r];
      }
    }
    uint32_t p0 = packbf(acc[ct][0], acc[ct][1]);
    uint32_t p1 = packbf(acc[ct][2], acc[ct][3]);
    uint32_t* dsth = hf_u + ((ct*4+ks_h)*64 + kgp*16 + of)*4 + vv;
    *(uint2*)dsth = make_uint2(p0, p1);
  }
  __syncthreads();

  // ---------- Phase 2: softmax(lrelu(src+dst)) @ h, fused elu + W2 dot ----------
  // ks outer / rt inner: dst + h-frag loaded once per ks, reused over 4 row-tiles.
  const int lhd = w >> 1;                     // 2 waves per head
  const int ghd = half*4 + lhd;
  const int rtb = (w&1)*4;                    // this wave's row-tile base
  float b1v  = b1[of];
  float w2c0 = w2[s*256 + (ghd*16+of)*2 + 0];
  float w2c1 = w2[s*256 + (ghd*16+of)*2 + 1];
  float srcv[4];
  #pragma unroll
  for (int r=0; r<4; ++r) srcv[r] = src_l[lhd*128 + (rtb+r)*16 + of];

  floatx4 acc2[4];
  float zp[4];
  #pragma unroll
  for (int r=0; r<4; ++r){ acc2[r]=(floatx4){0.f,0.f,0.f,0.f}; zp[r]=0.f; }

  #pragma unroll
  for (int ks=0; ks<4; ++ks){
    const float* dp = dst_l + lhd*128 + ks*32 + kg*8;
    float4 d0 = *(const float4*)dp, d1 = *(const float4*)(dp+4);
    float dj[8] = {d0.x,d0.y,d0.z,d0.w,d1.x,d1.y,d1.z,d1.w};
    short8 hbk = *(const short8*)(hf + ((lhd*4+ks)*64 + lane)*16);
    #pragma unroll
    for (int rt=0; rt<4; ++rt){
      const int im = (rtb+rt)*16 + of;
      uint32_t mbyte = mask_l[im*4 + ks] >> (kg*8);
      float e[8];
      #pragma unroll
      for (int jj=0; jj<8; ++jj){
        float t0 = srcv[rt] + dj[jj];         // already x log2e
        float lr = fmaxf(t0, 0.2f*t0);
        float ev = EXP2F(lr);
        ev = ((mbyte>>jj)&1u) ? ev : 0.f;
        e[jj]=ev; zp[rt] += ev;
      }
      F8 fr;
      fr.u[0]=packbf_t(e[0],e[1]); fr.u[1]=packbf_t(e[2],e[3]);
      fr.u[2]=packbf_t(e[4],e[5]); fr.u[3]=packbf_t(e[6],e[7]);
      acc2[rt] = __builtin_amdgcn_mfma_f32_16x16x32_bf16(fr.s8, hbk, acc2[rt], 0,0,0);
    }
  }

  #pragma unroll
  for (int rt=0; rt<4; ++rt){
    float zr = zp[rt] + __shfl_xor(zp[rt],16); zr += __shfl_xor(zr,32);
    float zi = __builtin_amdgcn_rcpf(zr);
    float pc0[4], pc1[4];
    #pragma unroll
    for (int r=0; r<4; ++r){
      float ziR = __shfl(zi, kg*4+r);
      float o  = fmaf(acc2[rt][r], ziR, b1v);
      float oe = (o>0.f) ? o : (__expf(o)-1.f);   // elu
      pc0[r] = red16(oe*w2c0);
      pc1[r] = red16(oe*w2c1);
    }
    if (of==0){
      #pragma unroll
      for (int r=0; r<4; ++r){
        int i = (rtb+rt)*16 + kg*4 + r;
        h2p[lhd*128 + i] = make_float2(pc0[r], pc1[r]);
      }
    }
  }
  __syncthreads();

  // ---------- block-partial h2 (sum over this block's 4 heads) -> ws ----------
  if (t < 256){
    const int jn = t>>1, cc = t&1;
    float hv = 0.f;
    #pragma unroll
    for (int hd2=0; hd2<4; ++hd2){
      float2 p = h2p[hd2*128+jn];
      hv += cc ? p.y : p.x;
    }
    ws_h2[(size_t)blk*256 + t] = hv;
  }
}

// ---- tail: layer-2 ego-row softmax + log_softmax + mean over S ----
__global__ __launch_bounds__(256) void gat_tail(
    const float* __restrict__ ws_h2, const int* __restrict__ adj,
    const float* __restrict__ a_src2, const float* __restrict__ a_dst2,
    const float* __restrict__ b2, float* __restrict__ out)
{
  __shared__ float d2_l[128];
  __shared__ float red[16];
  __shared__ float srcE;
  const int bb = blockIdx.x, t = threadIdx.x;
  const int jn = t>>1, cc = t&1, lane = t&63, w = t>>6;
  const uint32_t bit = (adj[((size_t)bb*128+127)*128 + jn] != 0) ? 1u : 0u;
  float acc0=0.f, acc1=0.f;
  for (int s=0; s<4; ++s){
    float hv = ws_h2[(size_t)(s*256 + bb*2 + 0)*256 + t]
             + ws_h2[(size_t)(s*256 + bb*2 + 1)*256 + t];
    float th2 = fast_tanh(hv);
    float ps2 = th2*a_src2[s*2+cc];
    float pd2 = th2*a_dst2[s*2+cc];
    ps2 += __shfl_xor(ps2,1);
    pd2 += __shfl_xor(pd2,1);
    if (s) __syncthreads();                  // WAR on d2_l/srcE/red
    if (cc==0) d2_l[jn]=pd2;
    if (t==254) srcE=ps2;                    // ego node jn=127
    __syncthreads();
    float t0 = srcE + d2_l[jn];
    float lg = fmaxf(t0, 0.2f*t0);
    float v  = bit ? lg : -1e9f;
    float mloc = v;
    #pragma unroll
    for (int off=32; off>=1; off>>=1) mloc = fmaxf(mloc, __shfl_xor(mloc,off));
    if (lane==0) red[w]=mloc;
    __syncthreads();
    float M = fmaxf(fmaxf(red[0],red[1]), fmaxf(red[2],red[3]));
    float e2 = __expf(v-M);
    float vA = e2*hv;
    float vZ = (cc==0) ? e2 : 0.f;
    #pragma unroll
    for (int off=2; off<=32; off<<=1){ vA+=__shfl_xor(vA,off); vZ+=__shfl_xor(vZ,off); }
    if (lane==0){ red[4+w]=vA; red[12+w]=vZ; }
    if (lane==1){ red[8+w]=vA; }
    __syncthreads();
    if (t==0){
      float S0 = red[4]+red[5]+red[6]+red[7];
      float S1 = red[8]+red[9]+red[10]+red[11];
      float Z  = red[12]+red[13]+red[14]+red[15];
      float o0 = S0/Z + b2[0];
      float o1 = S1/Z + b2[1];
      float mm = fmaxf(o0,o1);
      float lse = mm + logf(__expf(o0-mm)+__expf(o1-mm));
      acc0 += 0.25f*(o0 - lse);
      acc1 += 0.25f*(o1 - lse);
    }
  }
  if (t==0){ out[bb*2+0]=acc0; out[bb*2+1]=acc1; }
}

extern "C" void kernel_launch(void* const* d_in, const int* in_sizes, int n_in,
                              void* d_out, int out_size, void* d_ws, size_t ws_size,
                              hipStream_t stream) {
  const float* x      = (const float*)d_in[0];
  const float* emb    = (const float*)d_in[1];
  const int*   adj    = (const int*)d_in[2];
  const float* w1     = (const float*)d_in[3];
  const float* a_src1 = (const float*)d_in[4];
  const float* a_dst1 = (const float*)d_in[5];
  const float* b1     = (const float*)d_in[6];
  const float* w2     = (const float*)d_in[7];
  const float* a_src2 = (const float*)d_in[8];
  const float* a_dst2 = (const float*)d_in[9];
  const float* b2     = (const float*)d_in[10];

  float* ws_h2 = (float*)d_ws;   // 1024 blocks x 256 floats = 1 MB

  gat_fused<<<dim3(1024), dim3(512), 0, stream>>>(x, emb, adj, w1, a_src1, a_dst1,
                                                  b1, w2, ws_h2);
  gat_tail<<<dim3(128), dim3(256), 0, stream>>>(ws_h2, adj, a_src2, a_dst2, b2,
                                                (float*)d_out);
}

// Round 7
// 129.420 us; speedup vs baseline: 1.3547x; 1.3547x over previous
//
#include <hip/hip_runtime.h>
#include <stdint.h>
#include <math.h>

typedef __attribute__((ext_vector_type(8))) short short8;
typedef __attribute__((ext_vector_type(4))) float floatx4;

// ---------------- LDS layout (26624 B -> 4 blocks/CU at 8 waves) ----------------
#define L_HF    0        // 16384: W1 B-frags, then h B-frags: [ct(4)][ks(4)][lane(64)] x 16B
#define L_SRC   16384    // 2048 : att_src [4][128] f32 (pre-scaled by log2e)
#define L_DST   18432    // 2048 : att_dst [4][128] f32 (pre-scaled by log2e)
#define L_MASK  20480    // 2048 : mask bits [128 rows][16 B]
#define L_H2P   22528    // 4096 : layer-2 partials float2[4 heads][128 nodes]
#define L_SIZE  26624

union F8 { short8 s8; uint32_t u[4]; };

#if __has_builtin(__builtin_amdgcn_exp2f)
#define EXP2F __builtin_amdgcn_exp2f
#else
#define EXP2F exp2f
#endif
#define LOG2E 1.4426950408889634f

__device__ __forceinline__ uint32_t packbf(float a, float b){
  uint32_t ua = __float_as_uint(a), ub = __float_as_uint(b);
  uint32_t ra = (ua + 0x7fffu + ((ua>>16)&1u)) >> 16;   // RNE bf16
  uint32_t rb = (ub + 0x7fffu + ((ub>>16)&1u)) >> 16;
  return ra | (rb<<16);
}
// truncation pack (1 inst): low16 = hi16(a), high16 = hi16(b)
__device__ __forceinline__ uint32_t packbf_t(float a, float b){
  return __builtin_amdgcn_perm(__float_as_uint(b), __float_as_uint(a), 0x07060302u);
}
__device__ __forceinline__ float fast_tanh(float x){
  float e = __expf(2.f*x);
  return 1.f - 2.f*__builtin_amdgcn_rcpf(e + 1.f);
}
// sum over the 16-lane DPP row via row_ror — result valid in ALL lanes. Pure VALU.
__device__ __forceinline__ float red16(float x){
  x += __int_as_float(__builtin_amdgcn_update_dpp(0, __float_as_int(x), 0x128, 0xf, 0xf, true)); // row_ror:8
  x += __int_as_float(__builtin_amdgcn_update_dpp(0, __float_as_int(x), 0x124, 0xf, 0xf, true)); // row_ror:4
  x += __int_as_float(__builtin_amdgcn_update_dpp(0, __float_as_int(x), 0x122, 0xf, 0xf, true)); // row_ror:2
  x += __int_as_float(__builtin_amdgcn_update_dpp(0, __float_as_int(x), 0x121, 0xf, 0xf, true)); // row_ror:1
  return x;
}

// ---- fused GAT: one block per (s, b, head-half), 8 waves ----
__global__ __launch_bounds__(512,8) void gat_fused(
    const float* __restrict__ x,  const float* __restrict__ emb,
    const int* __restrict__ adj,  const float* __restrict__ w1,
    const float* __restrict__ a_src1, const float* __restrict__ a_dst1,
    const float* __restrict__ b1, const float* __restrict__ w2,
    float* __restrict__ ws_h2)
{
  __shared__ __align__(16) char smem[L_SIZE];
  char*     hf    = smem + L_HF;
  uint32_t* hf_u  = (uint32_t*)(smem + L_HF);
  float*    src_l = (float*)(smem + L_SRC);
  float*    dst_l = (float*)(smem + L_DST);
  uint32_t* mask_l= (uint32_t*)(smem + L_MASK);
  const uint4* mask4 = (const uint4*)(smem + L_MASK);
  float2*   h2p   = (float2*)(smem + L_H2P);

  const int t    = threadIdx.x;
  const int blk  = blockIdx.x;
  const int s    = blk >> 8;
  const int bb   = (blk & 255) >> 1;
  const int half = blk & 1;
  const int lane = t & 63, w = t >> 6;
  const int of = lane & 15, kg = lane >> 4;

  // ---------- Phase 0a: A-frags direct from global (rows w*16+of) ----------
  const int arow = w*16 + of;
  const float* xrow = x   + ((size_t)bb*128 + arow)*64;
  const float* erow = emb + ((size_t)bb*128 + arow)*64;
  short8 af[4];
  #pragma unroll
  for (int ks=0; ks<4; ++ks){
    int k = ks*32 + kg*8;
    const float* p = (k<64) ? (xrow+k) : (erow + (k-64));
    float4 f0 = *(const float4*)p, f1 = *(const float4*)(p+4);
    F8 fr;
    fr.u[0]=packbf(f0.x,f0.y); fr.u[1]=packbf(f0.z,f0.w);
    fr.u[2]=packbf(f1.x,f1.y); fr.u[3]=packbf(f1.z,f1.w);
    af[ks]=fr.s8;
  }

  // ---------- Phase 0b: stage this block's 4 heads of W1 as bf16 B-frags ----------
  {
    const float* w1s = w1 + (size_t)s*16384 + half*8192;  // 4 heads x 128 x 16
    #pragma unroll
    for (int r=0; r<2; ++r){
      int q = t + r*512;                     // 0..1023 = (ct*4+ks)*64 + qlane
      int ql = q & 63, ks = (q>>6)&3, ct = q>>8;
      const float* wp = w1s + ct*2048 + (ks*32 + (ql>>4)*8)*16 + (ql&15);
      F8 fr;
      fr.u[0]=packbf(wp[0],  wp[16]);
      fr.u[1]=packbf(wp[32], wp[48]);
      fr.u[2]=packbf(wp[64], wp[80]);
      fr.u[3]=packbf(wp[96], wp[112]);
      *(short8*)(hf + ((ct*4+ks)*64 + ql)*16) = fr.s8;
    }
  }

  // ---------- Phase 0c: adjacency ballot -> mask bits (wave w: rows w*16..+15) ----------
  {
    const int* adjb = adj + (size_t)bb*16384;
    #pragma unroll 4
    for (int rr=0; rr<16; ++rr){
      const int row = w*16 + rr;
      const int* ar = adjb + row*128;
      uint64_t m0 = __ballot(ar[lane] != 0);
      uint64_t m1 = __ballot(ar[64+lane] != 0);
      if (lane == 0)
        ((uint4*)mask_l)[row] = make_uint4((uint32_t)m0,(uint32_t)(m0>>32),
                                           (uint32_t)m1,(uint32_t)(m1>>32));
    }
  }
  __syncthreads();

  // ---------- Phase 1: h = x0 @ W1 via MFMA ----------
  floatx4 acc[4];
  #pragma unroll
  for (int ct=0; ct<4; ++ct) acc[ct]=(floatx4){0.f,0.f,0.f,0.f};
  #pragma unroll
  for (int ct=0; ct<4; ++ct)
    #pragma unroll
    for (int ks=0; ks<4; ++ks){
      short8 bfr = *(const short8*)(hf + ((ct*4+ks)*64 + lane)*16);
      acc[ct] = __builtin_amdgcn_mfma_f32_16x16x32_bf16(af[ks], bfr, acc[ct], 0,0,0);
    }
  __syncthreads();                            // all W1-frag reads done before h overwrite

  // epilogue: tanh -> att partials (x log2e) via DPP row-reduce; h -> LDS in B-frag order
  const int ks_h = w>>1, kgp = (w&1)*2 + (kg>>1), vv = (kg&1)*2;
  #pragma unroll
  for (int ct=0; ct<4; ++ct){
    const int ghd = half*4 + ct;
    float asv = a_src1[s*128 + ghd*16 + of] * LOG2E;
    float adv = a_dst1[s*128 + ghd*16 + of] * LOG2E;
    float ps[4], pd[4];
    #pragma unroll
    for (int r=0; r<4; ++r){
      float th = fast_tanh(acc[ct][r]);
      ps[r] = red16(th*asv); pd[r] = red16(th*adv);
    }
    if (of==0){
      #pragma unroll
      for (int r=0; r<4; ++r){
        int i = w*16 + kg*4 + r;
        src_l[ct*128+i]=ps[r]; dst_l[ct*128+i]=pd[r];
      }
    }
    uint32_t p0 = packbf(acc[ct][0], acc[ct][1]);
    uint32_t p1 = packbf(acc[ct][2], acc[ct][3]);
    uint32_t* dsth = hf_u + ((ct*4+ks_h)*64 + kgp*16 + of)*4 + vv;
    *(uint2*)dsth = make_uint2(p0, p1);
  }
  __syncthreads();

  // ---------- Phase 2: softmax(lrelu(src+dst)) @ h, fused elu + W2 dot ----------
  // rt outer / ks inner (R4 shape: single acc2/zp live -> no spills under the 8-wave bound)
  const int lhd = w >> 1;                     // 2 waves per head
  const int ghd = half*4 + lhd;
  const int rtb = (w&1)*4;                    // this wave's row-tile base
  float b1v  = b1[of];
  float w2c0 = w2[s*256 + (ghd*16+of)*2 + 0];
  float w2c1 = w2[s*256 + (ghd*16+of)*2 + 1];
  short8 hb[4];
  #pragma unroll
  for (int ks=0; ks<4; ++ks)
    hb[ks] = *(const short8*)(hf + ((lhd*4+ks)*64 + lane)*16);

  #pragma unroll
  for (int rtl=0; rtl<4; ++rtl){
    const int rt = rtb + rtl;
    const int im = rt*16 + of;                // A-layout row
    float srcv = src_l[lhd*128 + im];
    uint4 mrow = mask4[im];
    floatx4 acc2 = (floatx4){0.f,0.f,0.f,0.f};
    float zp = 0.f;
    #pragma unroll
    for (int ks=0; ks<4; ++ks){
      const float* dp = dst_l + lhd*128 + ks*32 + kg*8;
      float4 d0 = *(const float4*)dp, d1 = *(const float4*)(dp+4);
      uint32_t mw = (ks==0)?mrow.x:(ks==1)?mrow.y:(ks==2)?mrow.z:mrow.w;
      uint32_t mbyte = mw >> (kg*8);
      float dj[8] = {d0.x,d0.y,d0.z,d0.w,d1.x,d1.y,d1.z,d1.w};
      float e[8];
      #pragma unroll
      for (int jj=0; jj<8; ++jj){
        float t0 = srcv + dj[jj];             // already x log2e
        float lr = fmaxf(t0, 0.2f*t0);
        float ev = EXP2F(lr);
        ev = ((mbyte>>jj)&1u) ? ev : 0.f;
        e[jj]=ev; zp += ev;
      }
      F8 fr;
      fr.u[0]=packbf_t(e[0],e[1]); fr.u[1]=packbf_t(e[2],e[3]);
      fr.u[2]=packbf_t(e[4],e[5]); fr.u[3]=packbf_t(e[6],e[7]);
      acc2 = __builtin_amdgcn_mfma_f32_16x16x32_bf16(fr.s8, hb[ks], acc2, 0,0,0);
    }
    float zr = zp + __shfl_xor(zp,16); zr += __shfl_xor(zr,32);
    float zi = __builtin_amdgcn_rcpf(zr);
    float pc0[4], pc1[4];
    #pragma unroll
    for (int r=0; r<4; ++r){
      float ziR = __shfl(zi, kg*4+r);
      float o  = fmaf(acc2[r], ziR, b1v);
      float oe = (o>0.f) ? o : (__expf(o)-1.f);   // elu
      pc0[r] = red16(oe*w2c0);
      pc1[r] = red16(oe*w2c1);
    }
    if (of==0){
      #pragma unroll
      for (int r=0; r<4; ++r){
        int i = rt*16 + kg*4 + r;
        h2p[lhd*128 + i] = make_float2(pc0[r], pc1[r]);
      }
    }
  }
  __syncthreads();

  // ---------- block-partial h2 (sum over this block's 4 heads) -> ws ----------
  if (t < 256){
    const int jn = t>>1, cc = t&1;
    float hv = 0.f;
    #pragma unroll
    for (int hd2=0; hd2<4; ++hd2){
      float2 p = h2p[hd2*128+jn];
      hv += cc ? p.y : p.x;
    }
    ws_h2[(size_t)blk*256 + t] = hv;
  }
}

// ---- tail: layer-2 ego-row softmax + log_softmax + mean over S ----
__global__ __launch_bounds__(256) void gat_tail(
    const float* __restrict__ ws_h2, const int* __restrict__ adj,
    const float* __restrict__ a_src2, const float* __restrict__ a_dst2,
    const float* __restrict__ b2, float* __restrict__ out)
{
  __shared__ float d2_l[128];
  __shared__ float red[16];
  __shared__ float srcE;
  const int bb = blockIdx.x, t = threadIdx.x;
  const int jn = t>>1, cc = t&1, lane = t&63, w = t>>6;
  const uint32_t bit = (adj[((size_t)bb*128+127)*128 + jn] != 0) ? 1u : 0u;
  float acc0=0.f, acc1=0.f;
  for (int s=0; s<4; ++s){
    float hv = ws_h2[(size_t)(s*256 + bb*2 + 0)*256 + t]
             + ws_h2[(size_t)(s*256 + bb*2 + 1)*256 + t];
    float th2 = fast_tanh(hv);
    float ps2 = th2*a_src2[s*2+cc];
    float pd2 = th2*a_dst2[s*2+cc];
    ps2 += __shfl_xor(ps2,1);
    pd2 += __shfl_xor(pd2,1);
    if (s) __syncthreads();                  // WAR on d2_l/srcE/red
    if (cc==0) d2_l[jn]=pd2;
    if (t==254) srcE=ps2;                    // ego node jn=127
    __syncthreads();
    float t0 = srcE + d2_l[jn];
    float lg = fmaxf(t0, 0.2f*t0);
    float v  = bit ? lg : -1e9f;
    float mloc = v;
    #pragma unroll
    for (int off=32; off>=1; off>>=1) mloc = fmaxf(mloc, __shfl_xor(mloc,off));
    if (lane==0) red[w]=mloc;
    __syncthreads();
    float M = fmaxf(fmaxf(red[0],red[1]), fmaxf(red[2],red[3]));
    float e2 = __expf(v-M);
    float vA = e2*hv;
    float vZ = (cc==0) ? e2 : 0.f;
    #pragma unroll
    for (int off=2; off<=32; off<<=1){ vA+=__shfl_xor(vA,off); vZ+=__shfl_xor(vZ,off); }
    if (lane==0){ red[4+w]=vA; red[12+w]=vZ; }
    if (lane==1){ red[8+w]=vA; }
    __syncthreads();
    if (t==0){
      float S0 = red[4]+red[5]+red[6]+red[7];
      float S1 = red[8]+red[9]+red[10]+red[11];
      float Z  = red[12]+red[13]+red[14]+red[15];
      float o0 = S0/Z + b2[0];
      float o1 = S1/Z + b2[1];
      float mm = fmaxf(o0,o1);
      float lse = mm + logf(__expf(o0-mm)+__expf(o1-mm));
      acc0 += 0.25f*(o0 - lse);
      acc1 += 0.25f*(o1 - lse);
    }
  }
  if (t==0){ out[bb*2+0]=acc0; out[bb*2+1]=acc1; }
}

extern "C" void kernel_launch(void* const* d_in, const int* in_sizes, int n_in,
                              void* d_out, int out_size, void* d_ws, size_t ws_size,
                              hipStream_t stream) {
  const float* x      = (const float*)d_in[0];
  const float* emb    = (const float*)d_in[1];
  const int*   adj    = (const int*)d_in[2];
  const float* w1     = (const float*)d_in[3];
  const float* a_src1 = (const float*)d_in[4];
  const float* a_dst1 = (const float*)d_in[5];
  const float* b1     = (const float*)d_in[6];
  const float* w2     = (const float*)d_in[7];
  const float* a_src2 = (const float*)d_in[8];
  const float* a_dst2 = (const float*)d_in[9];
  const float* b2     = (const float*)d_in[10];

  float* ws_h2 = (float*)d_ws;   // 1024 blocks x 256 floats = 1 MB

  gat_fused<<<dim3(1024), dim3(512), 0, stream>>>(x, emb, adj, w1, a_src1, a_dst1,
                                                  b1, w2, ws_h2);
  gat_tail<<<dim3(128), dim3(256), 0, stream>>>(ws_h2, adj, a_src2, a_dst2, b2,
                                                (float*)d_out);
}